// Round 1
// baseline (333.312 us; speedup 1.0000x reference)
//
#include <hip/hip_runtime.h>
#include <cstdint>
#include <cstddef>

// ---------- types ----------
typedef float v4f  __attribute__((ext_vector_type(4)));
typedef __bf16 v8bf __attribute__((ext_vector_type(8)));

#define M_TOT 32768   // 8*64*64 tokens
#define KDIM  512
#define NQKV  1536
#define NPROJ 512

__device__ __constant__ float c_invf[8] = {
  1.f, 0.31622776601683794f, 0.1f, 0.031622776601683794f,
  0.01f, 0.0031622776601683794f, 0.001f, 0.00031622776601683794f };

__device__ __forceinline__ void async_copy16(const void* g, void* l) {
  __builtin_amdgcn_global_load_lds((const __attribute__((address_space(1))) void*)g,
                                   (__attribute__((address_space(3))) void*)l, 16, 0, 0);
}

// ---------- cast kernels ----------
__global__ void cast_x_kernel(const float* __restrict__ in, __bf16* __restrict__ out, int n8) {
  int i = blockIdx.x * blockDim.x + threadIdx.x;
  if (i >= n8) return;
  const float4* p = (const float4*)in + (size_t)i * 2;
  float4 a = p[0], b = p[1];
  v8bf r = { (__bf16)a.x, (__bf16)a.y, (__bf16)a.z, (__bf16)a.w,
             (__bf16)b.x, (__bf16)b.y, (__bf16)b.z, (__bf16)b.w };
  *(v8bf*)(out + (size_t)i * 8) = r;
}

// w[K][N] -> wt[N][K] bf16
__global__ void transpose_cast_kernel(const float* __restrict__ w, __bf16* __restrict__ wt,
                                      int K, int N) {
  int i = blockIdx.x * blockDim.x + threadIdx.x;
  if (i >= K * N) return;
  int k = i / N, n = i - k * N;
  wt[(size_t)n * K + k] = (__bf16)w[i];
}

// ---------- GEMM1: qkv = x @ qkv_w + b, epilogue: rope + scatter to q/k/v ----------
__global__ __launch_bounds__(256) void gemm_qkv(
    const __bf16* __restrict__ A,    // [M_TOT][512]
    const __bf16* __restrict__ Bt,   // [1536][512]
    const float* __restrict__ bias,  // [1536]
    __bf16* __restrict__ q_ws,       // [8192][64][32]
    __bf16* __restrict__ k_ws,       // [8192][64][32]
    __bf16* __restrict__ v_ws)       // [8192][32][64]
{
  __shared__ __bf16 As[128 * 32];
  __shared__ __bf16 Bs[128 * 32];
  const int tid  = threadIdx.x;
  const int lane = tid & 63;
  const int wave = tid >> 6;
  const int wm = wave >> 1, wn = wave & 1;
  const int m0 = blockIdx.x * 128, n0 = blockIdx.y * 128;
  const int lrow = lane & 15, quad = lane >> 4, kg = quad * 8;

  v4f acc[4][4] = {};

  for (int k0 = 0; k0 < KDIM; k0 += 32) {
#pragma unroll
    for (int i = 0; i < 2; ++i) {
      int e   = (i * 256 + tid) * 8;           // element in 128x32 tile (this lane)
      int row = e >> 5, kk = e & 31;
      int wbase = (i * 256 + (tid & ~63)) * 8; // wave-uniform LDS element base
      async_copy16(A  + (size_t)(m0 + row) * KDIM + k0 + kk, &As[wbase]);
      async_copy16(Bt + (size_t)(n0 + row) * KDIM + k0 + kk, &Bs[wbase]);
    }
    __syncthreads();
    v8bf af[4], bfr[4];
#pragma unroll
    for (int mi = 0; mi < 4; ++mi)
      af[mi] = *(const v8bf*)&As[(wm * 64 + mi * 16 + lrow) * 32 + kg];
#pragma unroll
    for (int ni = 0; ni < 4; ++ni)
      bfr[ni] = *(const v8bf*)&Bs[(wn * 64 + ni * 16 + lrow) * 32 + kg];
#pragma unroll
    for (int mi = 0; mi < 4; ++mi)
#pragma unroll
      for (int ni = 0; ni < 4; ++ni)
        acc[mi][ni] = __builtin_amdgcn_mfma_f32_16x16x32_bf16(af[mi], bfr[ni], acc[mi][ni], 0, 0, 0);
    __syncthreads();
  }

  // epilogue: bias + rope + scatter
  const int mb = m0 + wm * 64;
  const int nb = n0 + wn * 64;
#pragma unroll
  for (int ni = 0; ni < 4; ++ni) {
    int n    = nb + ni * 16 + lrow;
    int sel  = n >> 9;        // 0=q 1=k 2=v
    int c    = n & 511;
    int head = c >> 5;
    int hd   = c & 31;
    float bv = bias[n];
#pragma unroll
    for (int mi = 0; mi < 4; ++mi) {
#pragma unroll
      for (int r = 0; r < 4; ++r) {
        int m   = mb + mi * 16 + quad * 4 + r;
        float val = acc[mi][ni][r] + bv;
        int b   = m >> 12;
        int hh  = (m >> 6) & 63;
        int ww  = m & 63;
        int win = b * 64 + ((hh >> 3) << 3) + (ww >> 3);
        int tok = ((hh & 7) << 3) + (ww & 7);
        if (sel < 2) {
          // axial rope: pair element lives at lane^8 (hd^8 within 16-chunk)
          float partner = __shfl_xor(val, 8);
          int j8 = hd & 7;
          int p  = (hd < 16) ? (tok >> 3) : (tok & 7);   // height pos : width pos
          float ang = (float)p * c_invf[j8];
          float sv, cv;
          __sincosf(ang, &sv, &cv);
          float rh = (hd & 8) ? partner : -partner;
          val = val * cv + rh * sv;
          size_t idx = ((size_t)(win * 16 + head) * 64 + tok) * 32 + hd;
          if (sel == 0) q_ws[idx] = (__bf16)(val * 0.17677669529663689f);
          else          k_ws[idx] = (__bf16)val;
        } else {
          v_ws[((size_t)(win * 16 + head) * 32 + hd) * 64 + tok] = (__bf16)val;
        }
      }
    }
  }
}

// ---------- attention: one wave per (win, head) ----------
__global__ __launch_bounds__(256) void attn_win(
    const __bf16* __restrict__ q_ws, const __bf16* __restrict__ k_ws,
    const __bf16* __restrict__ v_ws, __bf16* __restrict__ attn_out)
{
  __shared__ __bf16 Ps[4][64 * 80];   // per-wave P buffer, padded row stride 80
  const int tid  = threadIdx.x;
  const int lane = tid & 63;
  const int wave = tid >> 6;
  const int pair = blockIdx.x * 4 + wave;   // 0..8191
  const int lrow = lane & 15, quad = lane >> 4, kg = quad * 8;

  const __bf16* qp = q_ws + (size_t)pair * 2048;  // [tok][hd]
  const __bf16* kp = k_ws + (size_t)pair * 2048;  // [tok][hd]
  const __bf16* vp = v_ws + (size_t)pair * 2048;  // [hd][tok]

  v8bf qf[4], kf[4];
#pragma unroll
  for (int i = 0; i < 4; ++i) qf[i] = *(const v8bf*)(qp + (i * 16 + lrow) * 32 + kg);
#pragma unroll
  for (int i = 0; i < 4; ++i) kf[i] = *(const v8bf*)(kp + (i * 16 + lrow) * 32 + kg);

  v4f s[4][4] = {};
#pragma unroll
  for (int mi = 0; mi < 4; ++mi)
#pragma unroll
    for (int ni = 0; ni < 4; ++ni)
      s[mi][ni] = __builtin_amdgcn_mfma_f32_16x16x32_bf16(qf[mi], kf[ni], s[mi][ni], 0, 0, 0);

  // softmax per query row (row = mi*16 + quad*4 + r, cols across ni & 16 lanes)
#pragma unroll
  for (int mi = 0; mi < 4; ++mi) {
#pragma unroll
    for (int r = 0; r < 4; ++r) {
      float mx = s[mi][0][r];
#pragma unroll
      for (int ni = 1; ni < 4; ++ni) mx = fmaxf(mx, s[mi][ni][r]);
      for (int d = 1; d < 16; d <<= 1) mx = fmaxf(mx, __shfl_xor(mx, d));
      float sum = 0.f;
#pragma unroll
      for (int ni = 0; ni < 4; ++ni) {
        float e = __expf(s[mi][ni][r] - mx);
        s[mi][ni][r] = e; sum += e;
      }
      for (int d = 1; d < 16; d <<= 1) sum += __shfl_xor(sum, d);
      float inv = 1.f / sum;
#pragma unroll
      for (int ni = 0; ni < 4; ++ni) s[mi][ni][r] *= inv;
    }
  }

  // C-layout -> A-layout via LDS
  __bf16* P = Ps[wave];
#pragma unroll
  for (int mi = 0; mi < 4; ++mi)
#pragma unroll
    for (int ni = 0; ni < 4; ++ni)
#pragma unroll
      for (int r = 0; r < 4; ++r)
        P[(mi * 16 + quad * 4 + r) * 80 + ni * 16 + lrow] = (__bf16)s[mi][ni][r];
  __syncthreads();

  v8bf pf[4][2], vf[2][2];
#pragma unroll
  for (int mi = 0; mi < 4; ++mi)
#pragma unroll
    for (int kc = 0; kc < 2; ++kc)
      pf[mi][kc] = *(const v8bf*)&P[(mi * 16 + lrow) * 80 + kc * 32 + kg];
#pragma unroll
  for (int kc = 0; kc < 2; ++kc)
#pragma unroll
    for (int nj = 0; nj < 2; ++nj)
      vf[kc][nj] = *(const v8bf*)(vp + (nj * 16 + lrow) * 64 + kc * 32 + kg);

  v4f o[4][2] = {};
#pragma unroll
  for (int mi = 0; mi < 4; ++mi)
#pragma unroll
    for (int nj = 0; nj < 2; ++nj)
#pragma unroll
      for (int kc = 0; kc < 2; ++kc)
        o[mi][nj] = __builtin_amdgcn_mfma_f32_16x16x32_bf16(pf[mi][kc], vf[kc][nj], o[mi][nj], 0, 0, 0);

  const int win = pair >> 4, head = pair & 15;
#pragma unroll
  for (int mi = 0; mi < 4; ++mi)
#pragma unroll
    for (int nj = 0; nj < 2; ++nj)
#pragma unroll
      for (int r = 0; r < 4; ++r) {
        int tokq = mi * 16 + quad * 4 + r;
        int ch   = head * 32 + nj * 16 + lrow;
        attn_out[((size_t)(win * 64 + tokq)) * 512 + ch] = (__bf16)o[mi][nj][r];
      }
}

// ---------- GEMM2: out = attn_out @ proj_w + b, permuted store ----------
__global__ __launch_bounds__(256) void gemm_proj(
    const __bf16* __restrict__ A,    // [M_TOT][512] window-row order
    const __bf16* __restrict__ Bt,   // [512][512]
    const float* __restrict__ bias,  // [512]
    float* __restrict__ out)         // [8][64][64][512] spatial
{
  __shared__ __bf16 As[128 * 32];
  __shared__ __bf16 Bs[128 * 32];
  const int tid  = threadIdx.x;
  const int lane = tid & 63;
  const int wave = tid >> 6;
  const int wm = wave >> 1, wn = wave & 1;
  const int m0 = blockIdx.x * 128, n0 = blockIdx.y * 128;
  const int lrow = lane & 15, quad = lane >> 4, kg = quad * 8;

  v4f acc[4][4] = {};

  for (int k0 = 0; k0 < KDIM; k0 += 32) {
#pragma unroll
    for (int i = 0; i < 2; ++i) {
      int e   = (i * 256 + tid) * 8;
      int row = e >> 5, kk = e & 31;
      int wbase = (i * 256 + (tid & ~63)) * 8;
      async_copy16(A  + (size_t)(m0 + row) * KDIM + k0 + kk, &As[wbase]);
      async_copy16(Bt + (size_t)(n0 + row) * KDIM + k0 + kk, &Bs[wbase]);
    }
    __syncthreads();
    v8bf af[4], bfr[4];
#pragma unroll
    for (int mi = 0; mi < 4; ++mi)
      af[mi] = *(const v8bf*)&As[(wm * 64 + mi * 16 + lrow) * 32 + kg];
#pragma unroll
    for (int ni = 0; ni < 4; ++ni)
      bfr[ni] = *(const v8bf*)&Bs[(wn * 64 + ni * 16 + lrow) * 32 + kg];
#pragma unroll
    for (int mi = 0; mi < 4; ++mi)
#pragma unroll
      for (int ni = 0; ni < 4; ++ni)
        acc[mi][ni] = __builtin_amdgcn_mfma_f32_16x16x32_bf16(af[mi], bfr[ni], acc[mi][ni], 0, 0, 0);
    __syncthreads();
  }

  const int mb = m0 + wm * 64;
  const int nb = n0 + wn * 64;
#pragma unroll
  for (int ni = 0; ni < 4; ++ni) {
    int n = nb + ni * 16 + lrow;
    float bv = bias[n];
#pragma unroll
    for (int mi = 0; mi < 4; ++mi) {
#pragma unroll
      for (int r = 0; r < 4; ++r) {
        int m    = mb + mi * 16 + quad * 4 + r;   // window-row index
        int win  = m >> 6, tok = m & 63;
        int b    = win >> 6;
        int hblk = (win >> 3) & 7, wblk = win & 7;
        int h    = hblk * 8 + (tok >> 3);
        int w    = wblk * 8 + (tok & 7);
        out[(((size_t)b * 64 + h) * 64 + w) * 512 + n] = acc[mi][ni][r] + bv;
      }
    }
  }
}

// ---------- launcher ----------
extern "C" void kernel_launch(void* const* d_in, const int* in_sizes, int n_in,
                              void* d_out, int out_size, void* d_ws, size_t ws_size,
                              hipStream_t stream) {
  (void)in_sizes; (void)n_in; (void)out_size; (void)ws_size;
  const float* x      = (const float*)d_in[0];
  const float* qkv_w  = (const float*)d_in[1];
  const float* qkv_b  = (const float*)d_in[2];
  // d_in[3] = kv_w, d_in[4] = kv_b: dead code in reference (hy_kv unused)
  const float* proj_w = (const float*)d_in[5];
  const float* proj_b = (const float*)d_in[6];
  float* out = (float*)d_out;

  char* ws = (char*)d_ws;
  size_t off = 0;
  auto alloc = [&](size_t bytes) {
    char* p = ws + off;
    off += (bytes + 255) & ~(size_t)255;
    return (void*)p;
  };
  __bf16* xb      = (__bf16*)alloc((size_t)M_TOT * KDIM * 2);   // also reused as attn_out
  __bf16* qkv_wt  = (__bf16*)alloc((size_t)NQKV * KDIM * 2);
  __bf16* proj_wt = (__bf16*)alloc((size_t)KDIM * KDIM * 2);
  __bf16* q_ws    = (__bf16*)alloc((size_t)M_TOT * KDIM * 2 / 3 * 1 + 0);   // placeholder, fixed below
  // NOTE: q/k/v are each M_TOT*512/... actually each is 8192*64*32 = 16.7M elems
  // re-do allocation cleanly:
  off = 0;
  xb      = (__bf16*)alloc((size_t)M_TOT * KDIM * 2);
  qkv_wt  = (__bf16*)alloc((size_t)NQKV * KDIM * 2);
  proj_wt = (__bf16*)alloc((size_t)KDIM * KDIM * 2);
  q_ws    = (__bf16*)alloc((size_t)8192 * 2048 * 2);
  __bf16* k_ws = (__bf16*)alloc((size_t)8192 * 2048 * 2);
  __bf16* v_ws = (__bf16*)alloc((size_t)8192 * 2048 * 2);
  __bf16* attn_out = xb;  // xb is dead after gemm_qkv; safe alias (stream-ordered)

  cast_x_kernel<<<dim3((M_TOT * KDIM / 8 + 255) / 256), dim3(256), 0, stream>>>(
      x, xb, M_TOT * KDIM / 8);
  transpose_cast_kernel<<<dim3((KDIM * NQKV + 255) / 256), dim3(256), 0, stream>>>(
      qkv_w, qkv_wt, KDIM, NQKV);
  transpose_cast_kernel<<<dim3((KDIM * NPROJ + 255) / 256), dim3(256), 0, stream>>>(
      proj_w, proj_wt, KDIM, NPROJ);

  gemm_qkv<<<dim3(M_TOT / 128, NQKV / 128), dim3(256), 0, stream>>>(
      xb, qkv_wt, qkv_b, q_ws, k_ws, v_ws);

  attn_win<<<dim3(8192 / 4), dim3(256), 0, stream>>>(q_ws, k_ws, v_ws, attn_out);

  gemm_proj<<<dim3(M_TOT / 128, NPROJ / 128), dim3(256), 0, stream>>>(
      attn_out, proj_wt, proj_b, out);
}

// Round 2
// 300.668 us; speedup vs baseline: 1.1086x; 1.1086x over previous
//
#include <hip/hip_runtime.h>
#include <cstdint>
#include <cstddef>

// ---------- types ----------
typedef float v4f  __attribute__((ext_vector_type(4)));
typedef __bf16 v8bf __attribute__((ext_vector_type(8)));
typedef __bf16 v4bf __attribute__((ext_vector_type(4)));

#define M_TOT 32768   // 8*64*64 tokens
#define KDIM  512
#define NQKV  1536
#define NPROJ 512

__device__ __constant__ float c_invf[8] = {
  1.f, 0.31622776601683794f, 0.1f, 0.031622776601683794f,
  0.01f, 0.0031622776601683794f, 0.001f, 0.00031622776601683794f };

__device__ __forceinline__ void async_copy16(const void* g, void* l) {
  __builtin_amdgcn_global_load_lds((const __attribute__((address_space(1))) void*)g,
                                   (__attribute__((address_space(3))) void*)l, 16, 0, 0);
}

// ---------- cast x -> bf16 ----------
__global__ void cast_x_kernel(const float* __restrict__ in, __bf16* __restrict__ out, int n8) {
  int i = blockIdx.x * blockDim.x + threadIdx.x;
  if (i >= n8) return;
  const float4* p = (const float4*)in + (size_t)i * 2;
  float4 a = p[0], b = p[1];
  v8bf r = { (__bf16)a.x, (__bf16)a.y, (__bf16)a.z, (__bf16)a.w,
             (__bf16)b.x, (__bf16)b.y, (__bf16)b.z, (__bf16)b.w };
  *(v8bf*)(out + (size_t)i * 8) = r;
}

// ---------- tiled transpose+cast: w[K][N] -> wt[N][K] bf16 ----------
// 64x64 tile via LDS: coalesced scalar loads, vectorized 16B stores.
__global__ __launch_bounds__(256) void transpose_cast_kernel(
    const float* __restrict__ w, __bf16* __restrict__ wt, int K, int N) {
  __shared__ __bf16 t[64 * 72];   // [nn][kk], pitch 72 (144B, 16B-aligned, conflict-free)
  const int tid = threadIdx.x;
  const int n0 = blockIdx.x * 64, k0 = blockIdx.y * 64;
#pragma unroll
  for (int i = 0; i < 16; ++i) {
    int e = i * 256 + tid;          // 0..4095
    int kk = e >> 6, nn = e & 63;   // consecutive tid -> nn (coalesced)
    t[nn * 72 + kk] = (__bf16)w[(size_t)(k0 + kk) * N + n0 + nn];
  }
  __syncthreads();
#pragma unroll
  for (int i = 0; i < 2; ++i) {
    int e = i * 256 + tid;          // 0..511 vector slots
    int nn = e >> 3, kc = e & 7;    // consecutive tid -> kc (128B global segments)
    *(v8bf*)&wt[(size_t)(n0 + nn) * K + k0 + kc * 8] = *(const v8bf*)&t[nn * 72 + kc * 8];
  }
}

// ---------- GEMM1: qkv = x @ qkv_w + b, rope + coalesced scatter ----------
__global__ __launch_bounds__(256) void gemm_qkv(
    const __bf16* __restrict__ A,    // [M_TOT][512]
    const __bf16* __restrict__ Bt,   // [1536][512]
    const float* __restrict__ bias,  // [1536]
    __bf16* __restrict__ q_ws,       // [8192][64][32]
    __bf16* __restrict__ k_ws,       // [8192][64][32]
    __bf16* __restrict__ v_ws)       // [8192][32][64]
{
  __shared__ __align__(16) char smem[34816];
  __bf16* As = (__bf16*)smem;              // [128][64] chunk-swizzled
  __bf16* Bs = (__bf16*)(smem + 16384);
  __bf16* Ct = (__bf16*)smem;              // epilogue tile, pitch 136

  const int tid  = threadIdx.x;
  const int lane = tid & 63;
  const int wave = tid >> 6;
  const int wm = wave >> 1, wn = wave & 1;
  const int m0 = blockIdx.x * 128, n0 = blockIdx.y * 128;
  const int lrow = lane & 15, quad = lane >> 4;

  v4f acc[4][4] = {};

  for (int k0 = 0; k0 < KDIM; k0 += 64) {
#pragma unroll
    for (int i = 0; i < 4; ++i) {
      int s   = i * 256 + tid;         // slot: row*8 + chunk'
      int row = s >> 3, c = s & 7;
      int q   = c ^ (row & 7);         // global chunk for this slot (swizzle)
      int wbase = (i * 256 + (tid & ~63)) * 8;
      async_copy16(A  + (size_t)(m0 + row) * KDIM + k0 + q * 8, &As[wbase]);
      async_copy16(Bt + (size_t)(n0 + row) * KDIM + k0 + q * 8, &Bs[wbase]);
    }
    __syncthreads();
#pragma unroll
    for (int kb = 0; kb < 2; ++kb) {
      int sx = (((kb << 2) | quad) ^ (lrow & 7)) * 8;
      v8bf af[4], bfr[4];
#pragma unroll
      for (int mi = 0; mi < 4; ++mi)
        af[mi] = *(const v8bf*)&As[(wm * 64 + mi * 16 + lrow) * 64 + sx];
#pragma unroll
      for (int ni = 0; ni < 4; ++ni)
        bfr[ni] = *(const v8bf*)&Bs[(wn * 64 + ni * 16 + lrow) * 64 + sx];
#pragma unroll
      for (int mi = 0; mi < 4; ++mi)
#pragma unroll
        for (int ni = 0; ni < 4; ++ni)
          acc[mi][ni] = __builtin_amdgcn_mfma_f32_16x16x32_bf16(af[mi], bfr[ni], acc[mi][ni], 0, 0, 0);
    }
    __syncthreads();
  }

  // ---- epilogue ----
  const int region = n0 >> 9;            // 0=q 1=k 2=v (uniform per block)
  const int head0  = (n0 & 511) >> 5;
  const int b      = m0 >> 12;
  const int H      = (m0 >> 6) & 63;     // even; tile rows H, H+1 in same window row
  const int Wr     = H >> 3, trow = H & 7;

  if (region < 2) {
    // rope in-register, stage Ct[m][n] (pitch 136), then 64B-row coalesced emit
#pragma unroll
    for (int ni = 0; ni < 4; ++ni) {
      int n_loc = wn * 64 + ni * 16 + lrow;
      int n     = n0 + n_loc;
      int hd    = n & 31;
      float bv  = bias[n];
      int j8    = hd & 7;
      float invf = c_invf[j8];
#pragma unroll
      for (int mi = 0; mi < 4; ++mi) {
#pragma unroll
        for (int r = 0; r < 4; ++r) {
          float val = acc[mi][ni][r] + bv;
          float partner = __shfl_xor(val, 8);
          int p = (hd < 16) ? (trow + wm) : ((quad * 4 + r) & 7);
          float ang = (float)p * invf;
          float sv, cv;
          __sincosf(ang, &sv, &cv);
          float rh = (hd & 8) ? partner : -partner;
          val = val * cv + rh * sv;
          if (region == 0) val *= 0.17677669529663689f;
          Ct[(wm * 64 + mi * 16 + quad * 4 + r) * 136 + n_loc] = (__bf16)val;
        }
      }
    }
    __syncthreads();
    __bf16* dst_base = region ? k_ws : q_ws;
#pragma unroll
    for (int e = 0; e < 2; ++e) {
      int R      = e * 256 + tid;       // head_i*128 + m_loc
      int head_i = R >> 7, m_loc = R & 127;
      int wblk   = (m_loc & 63) >> 3, mrow = m_loc >> 6;
      int tok    = (trow + mrow) * 8 + (m_loc & 7);
      int pair   = (b * 64 + Wr * 8 + wblk) * 16 + head0 + head_i;
      __bf16* dst = dst_base + ((size_t)pair * 64 + tok) * 32;
      const __bf16* src = &Ct[m_loc * 136 + head_i * 32];
#pragma unroll
      for (int j = 0; j < 4; ++j)
        *(v8bf*)(dst + j * 8) = *(const v8bf*)(src + j * 8);
    }
  } else {
    // v: stage Ct[n][m] (pitch 136) with packed b64 writes, emit 16B runs
#pragma unroll
    for (int ni = 0; ni < 4; ++ni) {
      int n_loc = wn * 64 + ni * 16 + lrow;
      float bv  = bias[n0 + n_loc];
#pragma unroll
      for (int mi = 0; mi < 4; ++mi) {
        v4bf pk;
#pragma unroll
        for (int r = 0; r < 4; ++r) pk[r] = (__bf16)(acc[mi][ni][r] + bv);
        *(v4bf*)&Ct[n_loc * 136 + wm * 64 + mi * 16 + quad * 4] = pk;
      }
    }
    __syncthreads();
#pragma unroll
    for (int e = 0; e < 4; ++e) {
      int R      = e * 256 + tid;       // ((head_i*8 + wblk)*32 + hd)
      int hd     = R & 31;
      int wblk   = (R >> 5) & 7;
      int head_i = R >> 8;
      int pair   = (b * 64 + Wr * 8 + wblk) * 16 + head0 + head_i;
      int n_loc  = head_i * 32 + hd;
      __bf16* dst = v_ws + ((size_t)pair * 32 + hd) * 64 + trow * 8;
      *(v8bf*)dst       = *(const v8bf*)&Ct[n_loc * 136 + wblk * 8];
      *(v8bf*)(dst + 8) = *(const v8bf*)&Ct[n_loc * 136 + 64 + wblk * 8];
    }
  }
}

// ---------- attention: one wave per (win, head) ----------
__global__ __launch_bounds__(256) void attn_win(
    const __bf16* __restrict__ q_ws, const __bf16* __restrict__ k_ws,
    const __bf16* __restrict__ v_ws, __bf16* __restrict__ attn_out)
{
  __shared__ __bf16 Ps[4][64 * 80];
  const int tid  = threadIdx.x;
  const int lane = tid & 63;
  const int wave = tid >> 6;
  const int pair = blockIdx.x * 4 + wave;
  const int lrow = lane & 15, quad = lane >> 4, kg = quad * 8;

  const __bf16* qp = q_ws + (size_t)pair * 2048;
  const __bf16* kp = k_ws + (size_t)pair * 2048;
  const __bf16* vp = v_ws + (size_t)pair * 2048;

  v8bf qf[4], kf[4];
#pragma unroll
  for (int i = 0; i < 4; ++i) qf[i] = *(const v8bf*)(qp + (i * 16 + lrow) * 32 + kg);
#pragma unroll
  for (int i = 0; i < 4; ++i) kf[i] = *(const v8bf*)(kp + (i * 16 + lrow) * 32 + kg);

  v4f s[4][4] = {};
#pragma unroll
  for (int mi = 0; mi < 4; ++mi)
#pragma unroll
    for (int ni = 0; ni < 4; ++ni)
      s[mi][ni] = __builtin_amdgcn_mfma_f32_16x16x32_bf16(qf[mi], kf[ni], s[mi][ni], 0, 0, 0);

#pragma unroll
  for (int mi = 0; mi < 4; ++mi) {
#pragma unroll
    for (int r = 0; r < 4; ++r) {
      float mx = s[mi][0][r];
#pragma unroll
      for (int ni = 1; ni < 4; ++ni) mx = fmaxf(mx, s[mi][ni][r]);
      for (int d = 1; d < 16; d <<= 1) mx = fmaxf(mx, __shfl_xor(mx, d));
      float sum = 0.f;
#pragma unroll
      for (int ni = 0; ni < 4; ++ni) {
        float e = __expf(s[mi][ni][r] - mx);
        s[mi][ni][r] = e; sum += e;
      }
      for (int d = 1; d < 16; d <<= 1) sum += __shfl_xor(sum, d);
      float inv = 1.f / sum;
#pragma unroll
      for (int ni = 0; ni < 4; ++ni) s[mi][ni][r] *= inv;
    }
  }

  __bf16* P = Ps[wave];
#pragma unroll
  for (int mi = 0; mi < 4; ++mi)
#pragma unroll
    for (int ni = 0; ni < 4; ++ni)
#pragma unroll
      for (int r = 0; r < 4; ++r)
        P[(mi * 16 + quad * 4 + r) * 80 + ni * 16 + lrow] = (__bf16)s[mi][ni][r];
  __syncthreads();

  v8bf pf[4][2], vf[2][2];
#pragma unroll
  for (int mi = 0; mi < 4; ++mi)
#pragma unroll
    for (int kc = 0; kc < 2; ++kc)
      pf[mi][kc] = *(const v8bf*)&P[(mi * 16 + lrow) * 80 + kc * 32 + kg];
#pragma unroll
  for (int kc = 0; kc < 2; ++kc)
#pragma unroll
    for (int nj = 0; nj < 2; ++nj)
      vf[kc][nj] = *(const v8bf*)(vp + (nj * 16 + lrow) * 64 + kc * 32 + kg);

  v4f o[4][2] = {};
#pragma unroll
  for (int mi = 0; mi < 4; ++mi)
#pragma unroll
    for (int nj = 0; nj < 2; ++nj)
#pragma unroll
      for (int kc = 0; kc < 2; ++kc)
        o[mi][nj] = __builtin_amdgcn_mfma_f32_16x16x32_bf16(pf[mi][kc], vf[kc][nj], o[mi][nj], 0, 0, 0);

  const int win = pair >> 4, head = pair & 15;
#pragma unroll
  for (int mi = 0; mi < 4; ++mi)
#pragma unroll
    for (int nj = 0; nj < 2; ++nj)
#pragma unroll
      for (int r = 0; r < 4; ++r) {
        int tokq = mi * 16 + quad * 4 + r;
        int ch   = head * 32 + nj * 16 + lrow;
        attn_out[((size_t)(win * 64 + tokq)) * 512 + ch] = (__bf16)o[mi][nj][r];
      }
}

// ---------- GEMM2: out = attn_out @ proj_w + b, permuted store ----------
__global__ __launch_bounds__(256) void gemm_proj(
    const __bf16* __restrict__ A,    // [M_TOT][512] window-row order
    const __bf16* __restrict__ Bt,   // [512][512]
    const float* __restrict__ bias,  // [512]
    float* __restrict__ out)         // [8][64][64][512] spatial
{
  __shared__ __align__(16) char smem[32768];
  __bf16* As = (__bf16*)smem;
  __bf16* Bs = (__bf16*)(smem + 16384);
  const int tid  = threadIdx.x;
  const int lane = tid & 63;
  const int wave = tid >> 6;
  const int wm = wave >> 1, wn = wave & 1;
  const int m0 = blockIdx.x * 128, n0 = blockIdx.y * 128;
  const int lrow = lane & 15, quad = lane >> 4;

  v4f acc[4][4] = {};

  for (int k0 = 0; k0 < KDIM; k0 += 64) {
#pragma unroll
    for (int i = 0; i < 4; ++i) {
      int s   = i * 256 + tid;
      int row = s >> 3, c = s & 7;
      int q   = c ^ (row & 7);
      int wbase = (i * 256 + (tid & ~63)) * 8;
      async_copy16(A  + (size_t)(m0 + row) * KDIM + k0 + q * 8, &As[wbase]);
      async_copy16(Bt + (size_t)(n0 + row) * KDIM + k0 + q * 8, &Bs[wbase]);
    }
    __syncthreads();
#pragma unroll
    for (int kb = 0; kb < 2; ++kb) {
      int sx = (((kb << 2) | quad) ^ (lrow & 7)) * 8;
      v8bf af[4], bfr[4];
#pragma unroll
      for (int mi = 0; mi < 4; ++mi)
        af[mi] = *(const v8bf*)&As[(wm * 64 + mi * 16 + lrow) * 64 + sx];
#pragma unroll
      for (int ni = 0; ni < 4; ++ni)
        bfr[ni] = *(const v8bf*)&Bs[(wn * 64 + ni * 16 + lrow) * 64 + sx];
#pragma unroll
      for (int mi = 0; mi < 4; ++mi)
#pragma unroll
        for (int ni = 0; ni < 4; ++ni)
          acc[mi][ni] = __builtin_amdgcn_mfma_f32_16x16x32_bf16(af[mi], bfr[ni], acc[mi][ni], 0, 0, 0);
    }
    __syncthreads();
  }

  const int mb = m0 + wm * 64;
  const int nb = n0 + wn * 64;
#pragma unroll
  for (int ni = 0; ni < 4; ++ni) {
    int n = nb + ni * 16 + lrow;
    float bv = bias[n];
#pragma unroll
    for (int mi = 0; mi < 4; ++mi) {
#pragma unroll
      for (int r = 0; r < 4; ++r) {
        int m    = mb + mi * 16 + quad * 4 + r;
        int win  = m >> 6, tok = m & 63;
        int bb   = win >> 6;
        int hblk = (win >> 3) & 7, wblk = win & 7;
        int h    = hblk * 8 + (tok >> 3);
        int w    = wblk * 8 + (tok & 7);
        out[(((size_t)bb * 64 + h) * 64 + w) * 512 + n] = acc[mi][ni][r] + bv;
      }
    }
  }
}

// ---------- launcher ----------
extern "C" void kernel_launch(void* const* d_in, const int* in_sizes, int n_in,
                              void* d_out, int out_size, void* d_ws, size_t ws_size,
                              hipStream_t stream) {
  (void)in_sizes; (void)n_in; (void)out_size; (void)ws_size;
  const float* x      = (const float*)d_in[0];
  const float* qkv_w  = (const float*)d_in[1];
  const float* qkv_b  = (const float*)d_in[2];
  // d_in[3]=kv_w, d_in[4]=kv_b: dead code in reference (hy_kv unused)
  const float* proj_w = (const float*)d_in[5];
  const float* proj_b = (const float*)d_in[6];
  float* out = (float*)d_out;

  char* ws = (char*)d_ws;
  size_t off = 0;
  auto alloc = [&](size_t bytes) {
    char* p = ws + off;
    off += (bytes + 255) & ~(size_t)255;
    return (void*)p;
  };
  __bf16* xb      = (__bf16*)alloc((size_t)M_TOT * KDIM * 2);
  __bf16* qkv_wt  = (__bf16*)alloc((size_t)NQKV * KDIM * 2);
  __bf16* proj_wt = (__bf16*)alloc((size_t)KDIM * KDIM * 2);
  __bf16* q_ws    = (__bf16*)alloc((size_t)8192 * 2048 * 2);
  __bf16* k_ws    = (__bf16*)alloc((size_t)8192 * 2048 * 2);
  __bf16* v_ws    = (__bf16*)alloc((size_t)8192 * 2048 * 2);
  __bf16* attn_out = xb;  // xb dead after gemm_qkv; stream-ordered reuse

  cast_x_kernel<<<dim3(M_TOT * KDIM / 8 / 256), dim3(256), 0, stream>>>(
      x, xb, M_TOT * KDIM / 8);
  transpose_cast_kernel<<<dim3(NQKV / 64, KDIM / 64), dim3(256), 0, stream>>>(
      qkv_w, qkv_wt, KDIM, NQKV);
  transpose_cast_kernel<<<dim3(NPROJ / 64, KDIM / 64), dim3(256), 0, stream>>>(
      proj_w, proj_wt, KDIM, NPROJ);

  gemm_qkv<<<dim3(M_TOT / 128, NQKV / 128), dim3(256), 0, stream>>>(
      xb, qkv_wt, qkv_b, q_ws, k_ws, v_ws);

  attn_win<<<dim3(8192 / 4), dim3(256), 0, stream>>>(q_ws, k_ws, v_ws, attn_out);

  gemm_proj<<<dim3(M_TOT / 128, NPROJ / 128), dim3(256), 0, stream>>>(
      attn_out, proj_wt, proj_b, out);
}

// Round 3
// 262.888 us; speedup vs baseline: 1.2679x; 1.1437x over previous
//
#include <hip/hip_runtime.h>
#include <cstdint>
#include <cstddef>

// ---------- types ----------
typedef float v4f  __attribute__((ext_vector_type(4)));
typedef __bf16 v8bf __attribute__((ext_vector_type(8)));
typedef __bf16 v4bf __attribute__((ext_vector_type(4)));

#define M_TOT 32768   // 8*64*64 tokens
#define KDIM  512
#define NQKV  1536
#define NPROJ 512

__device__ __constant__ float c_invf[8] = {
  1.f, 0.31622776601683794f, 0.1f, 0.031622776601683794f,
  0.01f, 0.0031622776601683794f, 0.001f, 0.00031622776601683794f };

__device__ __forceinline__ void async_copy16(const void* g, void* l) {
  __builtin_amdgcn_global_load_lds((const __attribute__((address_space(1))) void*)g,
                                   (__attribute__((address_space(3))) void*)l, 16, 0, 0);
}

// ---------- cast x -> bf16 ----------
__global__ void cast_x_kernel(const float* __restrict__ in, __bf16* __restrict__ out, int n8) {
  int i = blockIdx.x * blockDim.x + threadIdx.x;
  if (i >= n8) return;
  const float4* p = (const float4*)in + (size_t)i * 2;
  float4 a = p[0], b = p[1];
  v8bf r = { (__bf16)a.x, (__bf16)a.y, (__bf16)a.z, (__bf16)a.w,
             (__bf16)b.x, (__bf16)b.y, (__bf16)b.z, (__bf16)b.w };
  *(v8bf*)(out + (size_t)i * 8) = r;
}

// ---------- tiled transpose+cast: w[K][N] -> wt[N][K] bf16 ----------
__global__ __launch_bounds__(256) void transpose_cast_kernel(
    const float* __restrict__ w, __bf16* __restrict__ wt, int K, int N) {
  __shared__ __bf16 t[64 * 72];
  const int tid = threadIdx.x;
  const int n0 = blockIdx.x * 64, k0 = blockIdx.y * 64;
#pragma unroll
  for (int i = 0; i < 16; ++i) {
    int e = i * 256 + tid;
    int kk = e >> 6, nn = e & 63;
    t[nn * 72 + kk] = (__bf16)w[(size_t)(k0 + kk) * N + n0 + nn];
  }
  __syncthreads();
#pragma unroll
  for (int i = 0; i < 2; ++i) {
    int e = i * 256 + tid;
    int nn = e >> 3, kc = e & 7;
    *(v8bf*)&wt[(size_t)(n0 + nn) * K + k0 + kc * 8] = *(const v8bf*)&t[nn * 72 + kc * 8];
  }
}

// ---------- fused: qkv GEMM + rope + windowed attention ----------
// block: 256 thr (4 waves). tile: 128 tokens (2 windows, window-ordered rows)
//        x 96 cols (one head's q|k|v). grid: (256 m-tiles, 16 heads).
// LDS map (bytes):
//   [0,16384)      As 128x64 (swizzled)     | attn phase: per-wave P 4x(32x72)
//   [16384,28672)  Bs 96x64 (swizzled)      |             (P spans [0,18432))
//   [28672,58368)  qkv: 2 windows x { q 64x40 | k 64x40 | v 32x72 }
#define QKV_OFF   28672
#define WIN_STRIDE 14848   // bytes per window region
#define QK_PITCH  40
#define V_PITCH   72

__global__ __launch_bounds__(256) void gemm_qkv_attn(
    const __bf16* __restrict__ A,    // [M_TOT][512] bf16 (token order)
    const __bf16* __restrict__ Bt,   // [1536][512] bf16
    const float* __restrict__ bias,  // [1536]
    __bf16* __restrict__ attn_out)   // [512*64][512] window-row order
{
  __shared__ __align__(16) char smem[58368];
  __bf16* As = (__bf16*)smem;
  __bf16* Bs = (__bf16*)(smem + 16384);

  const int tid  = threadIdx.x;
  const int lane = tid & 63;
  const int wave = tid >> 6;
  const int lrow = lane & 15, quad = lane >> 4;
  const int head = blockIdx.y;

  // window bases for the 2 windows of this m-tile
  int mbase[2];
#pragma unroll
  for (int l = 0; l < 2; ++l) {
    int w  = blockIdx.x * 2 + l;
    int b  = w >> 6, Wr = (w >> 3) & 7, Wc = w & 7;
    mbase[l] = b * 4096 + Wr * 512 + Wc * 8;
  }

  v4f acc[2][6] = {};

  for (int k0 = 0; k0 < KDIM; k0 += 64) {
    // stage A: 128 rows (window order) x 8 chunks = 1024 slots
#pragma unroll
    for (int i = 0; i < 4; ++i) {
      int s   = i * 256 + tid;
      int row = s >> 3, c = s & 7;
      int qc  = c ^ (row & 7);
      int tok = row & 63;
      int m   = mbase[row >> 6] + ((tok >> 3) << 6) + (tok & 7);
      async_copy16(A + (size_t)m * KDIM + k0 + qc * 8, &As[(i * 256 + (tid & ~63)) * 8]);
    }
    // stage B: 96 rows (q|k|v of this head) x 8 chunks = 768 slots
#pragma unroll
    for (int i = 0; i < 3; ++i) {
      int s    = i * 256 + tid;
      int row  = s >> 3, c = s & 7;
      int qc   = c ^ (row & 7);
      int seg  = row >> 5;
      int grow = seg * 512 + head * 32 + (row & 31);
      async_copy16(Bt + (size_t)grow * KDIM + k0 + qc * 8, &Bs[(i * 256 + (tid & ~63)) * 8]);
    }
    __syncthreads();
#pragma unroll
    for (int kb = 0; kb < 2; ++kb) {
      int sx = (((kb << 2) | quad) ^ (lrow & 7)) * 8;
      v8bf af[2], bfr[6];
#pragma unroll
      for (int mi = 0; mi < 2; ++mi)
        af[mi] = *(const v8bf*)&As[(wave * 32 + mi * 16 + lrow) * 64 + sx];
#pragma unroll
      for (int ni = 0; ni < 6; ++ni)
        bfr[ni] = *(const v8bf*)&Bs[(ni * 16 + lrow) * 64 + sx];
#pragma unroll
      for (int mi = 0; mi < 2; ++mi)
#pragma unroll
        for (int ni = 0; ni < 6; ++ni)
          acc[mi][ni] = __builtin_amdgcn_mfma_f32_16x16x32_bf16(af[mi], bfr[ni], acc[mi][ni], 0, 0, 0);
    }
    __syncthreads();
  }

  // ---- epilogue: bias + rope, write q/k/v to LDS ----
  const int wloc = wave & 1;       // row-half within window
  const int win  = wave >> 1;      // local window 0/1
  __bf16* qL = (__bf16*)(smem + QKV_OFF + win * WIN_STRIDE);
  __bf16* kL = qL + 64 * QK_PITCH;
  __bf16* vL = kL + 64 * QK_PITCH;
  const int tokbase = 32 * wloc + quad * 4;

#pragma unroll
  for (int ni = 0; ni < 4; ++ni) {       // q (ni 0,1), k (ni 2,3)
    int c   = ni * 16 + lrow;
    int sel = c >> 5;
    int hd  = c & 31;
    float bv   = bias[sel * 512 + head * 32 + hd];
    float invf = c_invf[hd & 7];
    __bf16* dst = sel ? kL : qL;
#pragma unroll
    for (int mi = 0; mi < 2; ++mi) {
#pragma unroll
      for (int r = 0; r < 4; ++r) {
        int tok = tokbase + mi * 16 + r;
        float val = acc[mi][ni][r] + bv;
        float partner = __shfl_xor(val, 8);
        int p = (hd < 16) ? (tok >> 3) : (tok & 7);
        float ang = (float)p * invf;
        float sv, cv;
        __sincosf(ang, &sv, &cv);
        float rh = (hd & 8) ? partner : -partner;
        val = val * cv + rh * sv;
        if (sel == 0) val *= 0.17677669529663689f;
        dst[tok * QK_PITCH + hd] = (__bf16)val;
      }
    }
  }
#pragma unroll
  for (int ni = 4; ni < 6; ++ni) {       // v, transposed [hd][tok]
    int hd = (ni - 4) * 16 + lrow;
    float bv = bias[1024 + head * 32 + hd];
#pragma unroll
    for (int mi = 0; mi < 2; ++mi) {
      v4bf pk;
#pragma unroll
      for (int r = 0; r < 4; ++r) pk[r] = (__bf16)(acc[mi][ni][r] + bv);
      *(v4bf*)&vL[hd * V_PITCH + tokbase + mi * 16] = pk;
    }
  }
  __syncthreads();

  // ---- attention: wave handles 32 q-rows of its window ----
  v8bf qf[2], kf[4];
#pragma unroll
  for (int mi = 0; mi < 2; ++mi)
    qf[mi] = *(const v8bf*)&qL[(32 * wloc + mi * 16 + lrow) * QK_PITCH + quad * 8];
#pragma unroll
  for (int ni = 0; ni < 4; ++ni)
    kf[ni] = *(const v8bf*)&kL[(ni * 16 + lrow) * QK_PITCH + quad * 8];

  v4f S[2][4] = {};
#pragma unroll
  for (int mi = 0; mi < 2; ++mi)
#pragma unroll
    for (int ni = 0; ni < 4; ++ni)
      S[mi][ni] = __builtin_amdgcn_mfma_f32_16x16x32_bf16(qf[mi], kf[ni], S[mi][ni], 0, 0, 0);

#pragma unroll
  for (int mi = 0; mi < 2; ++mi) {
#pragma unroll
    for (int r = 0; r < 4; ++r) {
      float mx = S[mi][0][r];
#pragma unroll
      for (int ni = 1; ni < 4; ++ni) mx = fmaxf(mx, S[mi][ni][r]);
      for (int d = 1; d < 16; d <<= 1) mx = fmaxf(mx, __shfl_xor(mx, d));
      float sum = 0.f;
#pragma unroll
      for (int ni = 0; ni < 4; ++ni) {
        float e = __expf(S[mi][ni][r] - mx);
        S[mi][ni][r] = e; sum += e;
      }
      for (int d = 1; d < 16; d <<= 1) sum += __shfl_xor(sum, d);
      float inv = 1.f / sum;
#pragma unroll
      for (int ni = 0; ni < 4; ++ni) S[mi][ni][r] *= inv;
    }
  }

  // per-wave P buffer (aliases dead GEMM staging region)
  __bf16* Pw = (__bf16*)(smem + wave * 4608);
#pragma unroll
  for (int mi = 0; mi < 2; ++mi)
#pragma unroll
    for (int ni = 0; ni < 4; ++ni)
#pragma unroll
      for (int r = 0; r < 4; ++r)
        Pw[(mi * 16 + quad * 4 + r) * V_PITCH + ni * 16 + lrow] = (__bf16)S[mi][ni][r];
  __syncthreads();

  v8bf pf[2][2], vf[2][2];
#pragma unroll
  for (int mi = 0; mi < 2; ++mi)
#pragma unroll
    for (int kc = 0; kc < 2; ++kc)
      pf[mi][kc] = *(const v8bf*)&Pw[(mi * 16 + lrow) * V_PITCH + kc * 32 + quad * 8];
#pragma unroll
  for (int kc = 0; kc < 2; ++kc)
#pragma unroll
    for (int nj = 0; nj < 2; ++nj)
      vf[kc][nj] = *(const v8bf*)&vL[(nj * 16 + lrow) * V_PITCH + kc * 32 + quad * 8];

  v4f o[2][2] = {};
#pragma unroll
  for (int mi = 0; mi < 2; ++mi)
#pragma unroll
    for (int nj = 0; nj < 2; ++nj)
#pragma unroll
      for (int kc = 0; kc < 2; ++kc)
        o[mi][nj] = __builtin_amdgcn_mfma_f32_16x16x32_bf16(pf[mi][kc], vf[kc][nj], o[mi][nj], 0, 0, 0);

  const int gwin = blockIdx.x * 2 + win;
#pragma unroll
  for (int mi = 0; mi < 2; ++mi)
#pragma unroll
    for (int nj = 0; nj < 2; ++nj)
#pragma unroll
      for (int r = 0; r < 4; ++r) {
        int tok = 32 * wloc + mi * 16 + quad * 4 + r;
        int ch  = head * 32 + nj * 16 + lrow;
        attn_out[((size_t)gwin * 64 + tok) * 512 + ch] = (__bf16)o[mi][nj][r];
      }
}

// ---------- GEMM2: out = attn_out @ proj_w + b, permuted store ----------
__global__ __launch_bounds__(256) void gemm_proj(
    const __bf16* __restrict__ A,    // [M_TOT][512] window-row order
    const __bf16* __restrict__ Bt,   // [512][512]
    const float* __restrict__ bias,  // [512]
    float* __restrict__ out)         // [8][64][64][512] spatial
{
  __shared__ __align__(16) char smem[32768];
  __bf16* As = (__bf16*)smem;
  __bf16* Bs = (__bf16*)(smem + 16384);
  const int tid  = threadIdx.x;
  const int lane = tid & 63;
  const int wave = tid >> 6;
  const int wm = wave >> 1, wn = wave & 1;
  const int m0 = blockIdx.x * 128, n0 = blockIdx.y * 128;
  const int lrow = lane & 15, quad = lane >> 4;

  v4f acc[4][4] = {};

  for (int k0 = 0; k0 < KDIM; k0 += 64) {
#pragma unroll
    for (int i = 0; i < 4; ++i) {
      int s   = i * 256 + tid;
      int row = s >> 3, c = s & 7;
      int q   = c ^ (row & 7);
      int wbase = (i * 256 + (tid & ~63)) * 8;
      async_copy16(A  + (size_t)(m0 + row) * KDIM + k0 + q * 8, &As[wbase]);
      async_copy16(Bt + (size_t)(n0 + row) * KDIM + k0 + q * 8, &Bs[wbase]);
    }
    __syncthreads();
#pragma unroll
    for (int kb = 0; kb < 2; ++kb) {
      int sx = (((kb << 2) | quad) ^ (lrow & 7)) * 8;
      v8bf af[4], bfr[4];
#pragma unroll
      for (int mi = 0; mi < 4; ++mi)
        af[mi] = *(const v8bf*)&As[(wm * 64 + mi * 16 + lrow) * 64 + sx];
#pragma unroll
      for (int ni = 0; ni < 4; ++ni)
        bfr[ni] = *(const v8bf*)&Bs[(wn * 64 + ni * 16 + lrow) * 64 + sx];
#pragma unroll
      for (int mi = 0; mi < 4; ++mi)
#pragma unroll
        for (int ni = 0; ni < 4; ++ni)
          acc[mi][ni] = __builtin_amdgcn_mfma_f32_16x16x32_bf16(af[mi], bfr[ni], acc[mi][ni], 0, 0, 0);
    }
    __syncthreads();
  }

  const int mb = m0 + wm * 64;
  const int nb = n0 + wn * 64;
#pragma unroll
  for (int ni = 0; ni < 4; ++ni) {
    int n = nb + ni * 16 + lrow;
    float bv = bias[n];
#pragma unroll
    for (int mi = 0; mi < 4; ++mi) {
#pragma unroll
      for (int r = 0; r < 4; ++r) {
        int m    = mb + mi * 16 + quad * 4 + r;
        int win  = m >> 6, tok = m & 63;
        int bb   = win >> 6;
        int hblk = (win >> 3) & 7, wblk = win & 7;
        int h    = hblk * 8 + (tok >> 3);
        int w    = wblk * 8 + (tok & 7);
        out[(((size_t)bb * 64 + h) * 64 + w) * 512 + n] = acc[mi][ni][r] + bv;
      }
    }
  }
}

// ---------- launcher ----------
extern "C" void kernel_launch(void* const* d_in, const int* in_sizes, int n_in,
                              void* d_out, int out_size, void* d_ws, size_t ws_size,
                              hipStream_t stream) {
  (void)in_sizes; (void)n_in; (void)out_size; (void)ws_size;
  const float* x      = (const float*)d_in[0];
  const float* qkv_w  = (const float*)d_in[1];
  const float* qkv_b  = (const float*)d_in[2];
  // d_in[3]=kv_w, d_in[4]=kv_b: dead code in reference (hy_kv unused)
  const float* proj_w = (const float*)d_in[5];
  const float* proj_b = (const float*)d_in[6];
  float* out = (float*)d_out;

  char* ws = (char*)d_ws;
  size_t off = 0;
  auto alloc = [&](size_t bytes) {
    char* p = ws + off;
    off += (bytes + 255) & ~(size_t)255;
    return (void*)p;
  };
  __bf16* xb       = (__bf16*)alloc((size_t)M_TOT * KDIM * 2);
  __bf16* qkv_wt   = (__bf16*)alloc((size_t)NQKV * KDIM * 2);
  __bf16* proj_wt  = (__bf16*)alloc((size_t)KDIM * KDIM * 2);
  __bf16* attn_out = (__bf16*)alloc((size_t)M_TOT * KDIM * 2);

  cast_x_kernel<<<dim3(M_TOT * KDIM / 8 / 256), dim3(256), 0, stream>>>(
      x, xb, M_TOT * KDIM / 8);
  transpose_cast_kernel<<<dim3(NQKV / 64, KDIM / 64), dim3(256), 0, stream>>>(
      qkv_w, qkv_wt, KDIM, NQKV);
  transpose_cast_kernel<<<dim3(NPROJ / 64, KDIM / 64), dim3(256), 0, stream>>>(
      proj_w, proj_wt, KDIM, NPROJ);

  gemm_qkv_attn<<<dim3(256, 16), dim3(256), 0, stream>>>(
      xb, qkv_wt, qkv_b, attn_out);

  gemm_proj<<<dim3(M_TOT / 128, NPROJ / 128), dim3(256), 0, stream>>>(
      attn_out, proj_wt, proj_b, out);
}

// Round 4
// 261.982 us; speedup vs baseline: 1.2723x; 1.0035x over previous
//
#include <hip/hip_runtime.h>
#include <cstdint>
#include <cstddef>

// ---------- types ----------
typedef float v4f  __attribute__((ext_vector_type(4)));
typedef __bf16 v8bf __attribute__((ext_vector_type(8)));
typedef __bf16 v4bf __attribute__((ext_vector_type(4)));

#define M_TOT 32768   // 8*64*64 tokens
#define KDIM  512
#define NQKV  1536
#define NPROJ 512

__device__ __constant__ float c_invf[8] = {
  1.f, 0.31622776601683794f, 0.1f, 0.031622776601683794f,
  0.01f, 0.0031622776601683794f, 0.001f, 0.00031622776601683794f };

__device__ __forceinline__ void async_copy16(const void* g, void* l) {
  __builtin_amdgcn_global_load_lds((const __attribute__((address_space(1))) void*)g,
                                   (__attribute__((address_space(3))) void*)l, 16, 0, 0);
}

// ---------- cast x -> bf16 ----------
__global__ void cast_x_kernel(const float* __restrict__ in, __bf16* __restrict__ out, int n8) {
  int i = blockIdx.x * blockDim.x + threadIdx.x;
  if (i >= n8) return;
  const float4* p = (const float4*)in + (size_t)i * 2;
  float4 a = p[0], b = p[1];
  v8bf r = { (__bf16)a.x, (__bf16)a.y, (__bf16)a.z, (__bf16)a.w,
             (__bf16)b.x, (__bf16)b.y, (__bf16)b.z, (__bf16)b.w };
  *(v8bf*)(out + (size_t)i * 8) = r;
}

// ---------- tiled transpose+cast: w[K][N] -> wt[N][K] bf16 ----------
__global__ __launch_bounds__(256) void transpose_cast_kernel(
    const float* __restrict__ w, __bf16* __restrict__ wt, int K, int N) {
  __shared__ __bf16 t[64 * 72];
  const int tid = threadIdx.x;
  const int n0 = blockIdx.x * 64, k0 = blockIdx.y * 64;
#pragma unroll
  for (int i = 0; i < 16; ++i) {
    int e = i * 256 + tid;
    int kk = e >> 6, nn = e & 63;
    t[nn * 72 + kk] = (__bf16)w[(size_t)(k0 + kk) * N + n0 + nn];
  }
  __syncthreads();
#pragma unroll
  for (int i = 0; i < 2; ++i) {
    int e = i * 256 + tid;
    int nn = e >> 3, kc = e & 7;
    *(v8bf*)&wt[(size_t)(n0 + nn) * K + k0 + kc * 8] = *(const v8bf*)&t[nn * 72 + kc * 8];
  }
}

// ---------- fused: qkv GEMM + rope + windowed attention ----------
// block: 256 thr (4 waves). tile: 128 tokens (2 windows) x 192 cols (2 heads).
// wave w: window wl=w>>1, head-local hl=w&1 -> owns 64 tok x 96 cols, and the
// full attention for its (window, head). grid (8 head-pairs FAST, 256 m-tiles).
// LDS: staging As[0,16384) Bs[16384,40960); after K-loop: 4 regions x 14848 B
//      { q 64x40 | k 64x40 | v 32x72 }, P (64x72) aliases q+k of own region.
#define REG_STRIDE 14848
#define QK_PITCH  40
#define V_PITCH   72

__global__ __launch_bounds__(256) void gemm_qkv_attn(
    const __bf16* __restrict__ A,    // [M_TOT][512] bf16 (token order)
    const __bf16* __restrict__ Bt,   // [1536][512] bf16
    const float* __restrict__ bias,  // [1536]
    __bf16* __restrict__ attn_out)   // [512*64][512] window-row order
{
  __shared__ __align__(16) char smem[59392];
  __bf16* As = (__bf16*)smem;
  __bf16* Bs = (__bf16*)(smem + 16384);

  const int tid  = threadIdx.x;
  const int lane = tid & 63;
  const int wave = tid >> 6;
  const int lrow = lane & 15, quad = lane >> 4;
  const int hp   = blockIdx.x;      // head pair 0..7 (fast dim -> x reuse in L2)
  const int mt   = blockIdx.y;      // m-tile 0..255
  const int wl   = wave >> 1, hl = wave & 1;
  const int head = hp * 2 + hl;

  // window token bases
  int mbase[2];
#pragma unroll
  for (int l = 0; l < 2; ++l) {
    int w  = mt * 2 + l;
    int b  = w >> 6, Wr = (w >> 3) & 7, Wc = w & 7;
    mbase[l] = b * 4096 + Wr * 512 + Wc * 8;
  }

  // hoisted staging pointers (advance by 64 per K-iter)
  const __bf16* aptr[4]; __bf16* adst[4];
  const __bf16* bptr[6]; __bf16* bdst[6];
#pragma unroll
  for (int i = 0; i < 4; ++i) {
    int s = i * 256 + tid;
    int row = s >> 3, c = s & 7, qc = c ^ (row & 7);
    int tok = row & 63;
    int m = mbase[row >> 6] + ((tok >> 3) << 6) + (tok & 7);
    aptr[i] = A + (size_t)m * KDIM + qc * 8;
    adst[i] = &As[(i * 256 + (tid & ~63)) * 8];
  }
#pragma unroll
  for (int i = 0; i < 6; ++i) {
    int s = i * 256 + tid;
    int rl = s >> 3, c = s & 7, qc = c ^ (rl & 7);
    int sel = rl >> 6, rem = rl & 63;
    int grow = sel * 512 + (hp * 2 + (rem >> 5)) * 32 + (rem & 31);
    bptr[i] = Bt + (size_t)grow * KDIM + qc * 8;
    bdst[i] = &Bs[(i * 256 + (tid & ~63)) * 8];
  }

  v4f acc[4][6] = {};

  for (int k0 = 0; k0 < KDIM; k0 += 64) {
#pragma unroll
    for (int i = 0; i < 4; ++i) { async_copy16(aptr[i], adst[i]); aptr[i] += 64; }
#pragma unroll
    for (int i = 0; i < 6; ++i) { async_copy16(bptr[i], bdst[i]); bptr[i] += 64; }
    __syncthreads();
#pragma unroll
    for (int kb = 0; kb < 2; ++kb) {
      int sx = (((kb << 2) | quad) ^ (lrow & 7)) * 8;
      v8bf af[4], bfr[6];
#pragma unroll
      for (int mi = 0; mi < 4; ++mi)
        af[mi] = *(const v8bf*)&As[(wl * 64 + mi * 16 + lrow) * 64 + sx];
#pragma unroll
      for (int j = 0; j < 6; ++j)
        bfr[j] = *(const v8bf*)&Bs[((j >> 1) * 64 + hl * 32 + (j & 1) * 16 + lrow) * 64 + sx];
#pragma unroll
      for (int mi = 0; mi < 4; ++mi)
#pragma unroll
        for (int j = 0; j < 6; ++j)
          acc[mi][j] = __builtin_amdgcn_mfma_f32_16x16x32_bf16(af[mi], bfr[j], acc[mi][j], 0, 0, 0);
    }
    __syncthreads();   // last iter: also protects region aliasing below
  }

  // ---- epilogue: bias + rope -> wave-private LDS region (no barriers) ----
  __bf16* reg = (__bf16*)(smem + wave * REG_STRIDE);
  __bf16* qL = reg;
  __bf16* kL = reg + 64 * QK_PITCH;
  __bf16* vL = kL + 64 * QK_PITCH;

#pragma unroll
  for (int j = 0; j < 4; ++j) {          // q (j 0,1), k (j 2,3)
    int sel = j >> 1, nh = j & 1;
    int hd  = nh * 16 + lrow;
    float bv   = bias[sel * 512 + head * 32 + hd];
    float invf = c_invf[hd & 7];
    __bf16* dst = sel ? kL : qL;
#pragma unroll
    for (int mi = 0; mi < 4; ++mi) {
#pragma unroll
      for (int r = 0; r < 4; ++r) {
        int tok = mi * 16 + quad * 4 + r;
        float val = acc[mi][j][r] + bv;
        float partner = __shfl_xor(val, 8);
        int p = (hd < 16) ? (tok >> 3) : (tok & 7);
        float ang = (float)p * invf;
        float sv, cv;
        __sincosf(ang, &sv, &cv);
        float rh = (hd & 8) ? partner : -partner;
        val = val * cv + rh * sv;
        if (sel == 0) val *= 0.17677669529663689f;
        dst[tok * QK_PITCH + hd] = (__bf16)val;
      }
    }
  }
#pragma unroll
  for (int j = 4; j < 6; ++j) {          // v transposed [hd][tok]
    int hd = (j - 4) * 16 + lrow;
    float bv = bias[1024 + head * 32 + hd];
#pragma unroll
    for (int mi = 0; mi < 4; ++mi) {
      v4bf pk;
#pragma unroll
      for (int r = 0; r < 4; ++r) pk[r] = (__bf16)(acc[mi][j][r] + bv);
      *(v4bf*)&vL[hd * V_PITCH + mi * 16 + quad * 4] = pk;
    }
  }

  // ---- attention (wave-private) ----
  v8bf qf[4], kf[4];
#pragma unroll
  for (int mi = 0; mi < 4; ++mi)
    qf[mi] = *(const v8bf*)&qL[(mi * 16 + lrow) * QK_PITCH + quad * 8];
#pragma unroll
  for (int ni = 0; ni < 4; ++ni)
    kf[ni] = *(const v8bf*)&kL[(ni * 16 + lrow) * QK_PITCH + quad * 8];

  v4f S[4][4] = {};
#pragma unroll
  for (int mi = 0; mi < 4; ++mi)
#pragma unroll
    for (int ni = 0; ni < 4; ++ni)
      S[mi][ni] = __builtin_amdgcn_mfma_f32_16x16x32_bf16(qf[mi], kf[ni], S[mi][ni], 0, 0, 0);

#pragma unroll
  for (int mi = 0; mi < 4; ++mi) {
#pragma unroll
    for (int r = 0; r < 4; ++r) {
      float mx = S[mi][0][r];
#pragma unroll
      for (int ni = 1; ni < 4; ++ni) mx = fmaxf(mx, S[mi][ni][r]);
      for (int d = 1; d < 16; d <<= 1) mx = fmaxf(mx, __shfl_xor(mx, d));
      float sum = 0.f;
#pragma unroll
      for (int ni = 0; ni < 4; ++ni) {
        float e = __expf(S[mi][ni][r] - mx);
        S[mi][ni][r] = e; sum += e;
      }
      for (int d = 1; d < 16; d <<= 1) sum += __shfl_xor(sum, d);
      float inv = 1.f / sum;
#pragma unroll
      for (int ni = 0; ni < 4; ++ni) S[mi][ni][r] *= inv;
    }
  }

  // P (C-layout -> A-layout) through own region (aliases dead q+k)
  __bf16* P = reg;
#pragma unroll
  for (int mi = 0; mi < 4; ++mi)
#pragma unroll
    for (int ni = 0; ni < 4; ++ni)
#pragma unroll
      for (int r = 0; r < 4; ++r)
        P[(mi * 16 + quad * 4 + r) * V_PITCH + ni * 16 + lrow] = (__bf16)S[mi][ni][r];

  v8bf pf[4][2], vf[2][2];
#pragma unroll
  for (int mi = 0; mi < 4; ++mi)
#pragma unroll
    for (int kc = 0; kc < 2; ++kc)
      pf[mi][kc] = *(const v8bf*)&P[(mi * 16 + lrow) * V_PITCH + kc * 32 + quad * 8];
#pragma unroll
  for (int kc = 0; kc < 2; ++kc)
#pragma unroll
    for (int nj = 0; nj < 2; ++nj)
      vf[kc][nj] = *(const v8bf*)&vL[(nj * 16 + lrow) * V_PITCH + kc * 32 + quad * 8];

  v4f o[4][2] = {};
#pragma unroll
  for (int mi = 0; mi < 4; ++mi)
#pragma unroll
    for (int nj = 0; nj < 2; ++nj)
#pragma unroll
      for (int kc = 0; kc < 2; ++kc)
        o[mi][nj] = __builtin_amdgcn_mfma_f32_16x16x32_bf16(pf[mi][kc], vf[kc][nj], o[mi][nj], 0, 0, 0);

  const int gwin = mt * 2 + wl;
#pragma unroll
  for (int mi = 0; mi < 4; ++mi)
#pragma unroll
    for (int nj = 0; nj < 2; ++nj)
#pragma unroll
      for (int r = 0; r < 4; ++r) {
        int tok = mi * 16 + quad * 4 + r;
        int ch  = head * 32 + nj * 16 + lrow;
        attn_out[((size_t)gwin * 64 + tok) * 512 + ch] = (__bf16)o[mi][nj][r];
      }
}

// ---------- GEMM2: out = attn_out @ proj_w + b, permuted store ----------
// 256x128 tile, wave = 64 rows x 128 cols. grid (4 n FAST, 128 m) = 512 blocks.
__global__ __launch_bounds__(256) void gemm_proj(
    const __bf16* __restrict__ A,    // [M_TOT][512] window-row order
    const __bf16* __restrict__ Bt,   // [512][512]
    const float* __restrict__ bias,  // [512]
    float* __restrict__ out)         // [8][64][64][512] spatial
{
  __shared__ __align__(16) char smem[49152];
  __bf16* As = (__bf16*)smem;                  // 256x64
  __bf16* Bs = (__bf16*)(smem + 32768);        // 128x64
  const int tid  = threadIdx.x;
  const int lane = tid & 63;
  const int wave = tid >> 6;
  const int n0 = blockIdx.x * 128, m0 = blockIdx.y * 256;
  const int lrow = lane & 15, quad = lane >> 4;

  const __bf16* aptr[8]; __bf16* adst[8];
  const __bf16* bptr[4]; __bf16* bdst[4];
#pragma unroll
  for (int i = 0; i < 8; ++i) {
    int s = i * 256 + tid;
    int row = s >> 3, c = s & 7, qc = c ^ (row & 7);
    aptr[i] = A + (size_t)(m0 + row) * KDIM + qc * 8;
    adst[i] = &As[(i * 256 + (tid & ~63)) * 8];
  }
#pragma unroll
  for (int i = 0; i < 4; ++i) {
    int s = i * 256 + tid;
    int row = s >> 3, c = s & 7, qc = c ^ (row & 7);
    bptr[i] = Bt + (size_t)(n0 + row) * KDIM + qc * 8;
    bdst[i] = &Bs[(i * 256 + (tid & ~63)) * 8];
  }

  v4f acc[4][8] = {};

  for (int k0 = 0; k0 < KDIM; k0 += 64) {
#pragma unroll
    for (int i = 0; i < 8; ++i) { async_copy16(aptr[i], adst[i]); aptr[i] += 64; }
#pragma unroll
    for (int i = 0; i < 4; ++i) { async_copy16(bptr[i], bdst[i]); bptr[i] += 64; }
    __syncthreads();
#pragma unroll
    for (int kb = 0; kb < 2; ++kb) {
      int sx = (((kb << 2) | quad) ^ (lrow & 7)) * 8;
      v8bf af[4], bfr[8];
#pragma unroll
      for (int mi = 0; mi < 4; ++mi)
        af[mi] = *(const v8bf*)&As[(wave * 64 + mi * 16 + lrow) * 64 + sx];
#pragma unroll
      for (int ni = 0; ni < 8; ++ni)
        bfr[ni] = *(const v8bf*)&Bs[(ni * 16 + lrow) * 64 + sx];
#pragma unroll
      for (int mi = 0; mi < 4; ++mi)
#pragma unroll
        for (int ni = 0; ni < 8; ++ni)
          acc[mi][ni] = __builtin_amdgcn_mfma_f32_16x16x32_bf16(af[mi], bfr[ni], acc[mi][ni], 0, 0, 0);
    }
    __syncthreads();
  }

  const int mb = m0 + wave * 64;
#pragma unroll
  for (int ni = 0; ni < 8; ++ni) {
    int n = n0 + ni * 16 + lrow;
    float bv = bias[n];
#pragma unroll
    for (int mi = 0; mi < 4; ++mi) {
#pragma unroll
      for (int r = 0; r < 4; ++r) {
        int m    = mb + mi * 16 + quad * 4 + r;
        int win  = m >> 6, tok = m & 63;
        int bb   = win >> 6;
        int hblk = (win >> 3) & 7, wblk = win & 7;
        int h    = hblk * 8 + (tok >> 3);
        int w    = wblk * 8 + (tok & 7);
        out[(((size_t)bb * 64 + h) * 64 + w) * 512 + n] = acc[mi][ni][r] + bv;
      }
    }
  }
}

// ---------- launcher ----------
extern "C" void kernel_launch(void* const* d_in, const int* in_sizes, int n_in,
                              void* d_out, int out_size, void* d_ws, size_t ws_size,
                              hipStream_t stream) {
  (void)in_sizes; (void)n_in; (void)out_size; (void)ws_size;
  const float* x      = (const float*)d_in[0];
  const float* qkv_w  = (const float*)d_in[1];
  const float* qkv_b  = (const float*)d_in[2];
  // d_in[3]=kv_w, d_in[4]=kv_b: dead code in reference (hy_kv unused)
  const float* proj_w = (const float*)d_in[5];
  const float* proj_b = (const float*)d_in[6];
  float* out = (float*)d_out;

  char* ws = (char*)d_ws;
  size_t off = 0;
  auto alloc = [&](size_t bytes) {
    char* p = ws + off;
    off += (bytes + 255) & ~(size_t)255;
    return (void*)p;
  };
  __bf16* xb       = (__bf16*)alloc((size_t)M_TOT * KDIM * 2);
  __bf16* qkv_wt   = (__bf16*)alloc((size_t)NQKV * KDIM * 2);
  __bf16* proj_wt  = (__bf16*)alloc((size_t)KDIM * KDIM * 2);
  __bf16* attn_out = (__bf16*)alloc((size_t)M_TOT * KDIM * 2);

  cast_x_kernel<<<dim3(M_TOT * KDIM / 8 / 256), dim3(256), 0, stream>>>(
      x, xb, M_TOT * KDIM / 8);
  transpose_cast_kernel<<<dim3(NQKV / 64, KDIM / 64), dim3(256), 0, stream>>>(
      qkv_w, qkv_wt, KDIM, NQKV);
  transpose_cast_kernel<<<dim3(NPROJ / 64, KDIM / 64), dim3(256), 0, stream>>>(
      proj_w, proj_wt, KDIM, NPROJ);

  gemm_qkv_attn<<<dim3(8, 256), dim3(256), 0, stream>>>(
      xb, qkv_wt, qkv_b, attn_out);

  gemm_proj<<<dim3(4, 128), dim3(256), 0, stream>>>(
      attn_out, proj_wt, proj_b, out);
}